// Round 3
// baseline (115.298 us; speedup 1.0000x reference)
//
#include <hip/hip_runtime.h>

// Problem constants (B=2, S=512, D=128, DG=64, NG=2)
#define BQ 2
#define SQ 512
#define DQ 128
#define DGQ 64
#define NGQ 2

typedef float f32x4 __attribute__((ext_vector_type(4)));
typedef __bf16 bf16x8 __attribute__((ext_vector_type(8)));

// ws layout (floats):
//   QW1 : [B*S][128]          @ 0        (= (x@Wq)@blkdiag(W1) + b1, per group)
//   KW1 : [B*S][128]          @ 131072
//   Vp  : [B*S][NG][DG]       @ 262144   (group-major V for coalesced A@V)

// ---------------------------------------------------------------------------
// Kernel 1: fused projections, 4 rows per block (256 blocks x 512 thr).
// Phase A: Q,K,V for 4 rows via split-K over 4 quarters; each weight load
// feeds 4 FMAs (weight L2 traffic 1024->256 block-reads = 48 MB total).
// Phase B: QW1 = Q@blkdiag(W1)+b1, KW1 = K@blkdiag(W1)  (linearity trick:
// relu((Q_i-K_j)@W1 + b1) == relu(QW1_i - KW1_j)).
// ---------------------------------------------------------------------------
__global__ __launch_bounds__(512) void proj_kernel(
    const float* __restrict__ x,
    const float* __restrict__ Wq, const float* __restrict__ Wk,
    const float* __restrict__ Wv,
    const float* __restrict__ W1, const float* __restrict__ b1,
    float* __restrict__ QW1, float* __restrict__ KW1, float* __restrict__ Vp)
{
    const int t = threadIdx.x;
    const int row0 = blockIdx.x * 4;
    __shared__ float xs[4][DQ];
    __shared__ float part[3][4][4][DQ];     // [mat][quarter][row][feat] 24KB
    __shared__ float qs[4][DQ], ks[4][DQ];

    ((float*)xs)[t] = x[(size_t)row0 * DQ + t];
    __syncthreads();

    const int f = t & 127, h = t >> 7;      // feature, K-quarter
    const int d0 = h * 32;
    float aq[4] = {0.f, 0.f, 0.f, 0.f};
    float ak[4] = {0.f, 0.f, 0.f, 0.f};
    float av[4] = {0.f, 0.f, 0.f, 0.f};
    #pragma unroll 8
    for (int d = 0; d < 32; ++d) {
        const size_t o = (size_t)(d0 + d) * DQ + f;   // 256B/wave coalesced
        const float wq = Wq[o], wk = Wk[o], wv = Wv[o];
        #pragma unroll
        for (int r = 0; r < 4; ++r) {
            const float xv = xs[r][d0 + d];            // LDS broadcast
            aq[r] = fmaf(xv, wq, aq[r]);
            ak[r] = fmaf(xv, wk, ak[r]);
            av[r] = fmaf(xv, wv, av[r]);
        }
    }
    #pragma unroll
    for (int r = 0; r < 4; ++r) {
        part[0][h][r][f] = aq[r];
        part[1][h][r][f] = ak[r];
        part[2][h][r][f] = av[r];
    }
    __syncthreads();

    const int fc = t & 127, sel = t >> 7;
    if (sel == 0) {
        #pragma unroll
        for (int r = 0; r < 4; ++r)
            qs[r][fc] = part[0][0][r][fc] + part[0][1][r][fc] +
                        part[0][2][r][fc] + part[0][3][r][fc];
    } else if (sel == 1) {
        #pragma unroll
        for (int r = 0; r < 4; ++r)
            ks[r][fc] = part[1][0][r][fc] + part[1][1][r][fc] +
                        part[1][2][r][fc] + part[1][3][r][fc];
    } else if (sel == 2) {
        #pragma unroll
        for (int r = 0; r < 4; ++r) {
            const float v = part[2][0][r][fc] + part[2][1][r][fc] +
                            part[2][2][r][fc] + part[2][3][r][fc];
            // feature fc = dg*NG+g  ->  Vp[row][g][dg]
            Vp[((size_t)(row0 + r) * NGQ + (fc & 1)) * DGQ + (fc >> 1)] = v;
        }
    }
    __syncthreads();

    // Phase B: 512 tasks = {q,k} x 2 row-pairs x 128 features
    const int fb = t & 127, rp = (t >> 7) & 1, side = t >> 8;
    const int g = fb >> 6, c = fb & 63;
    const float* src = side ? &ks[0][0] : &qs[0][0];
    const int r0 = rp * 2;
    float a0 = side ? 0.f : b1[c];
    float a1 = a0;
    #pragma unroll 8
    for (int e = 0; e < 64; ++e) {
        const float w1v = W1[e * DGQ + c];             // 256B/wave coalesced
        a0 = fmaf(src[r0 * DQ + g * 64 + e], w1v, a0);
        a1 = fmaf(src[(r0 + 1) * DQ + g * 64 + e], w1v, a1);
    }
    float* dst = side ? KW1 : QW1;
    dst[(size_t)(row0 + r0) * DQ + fb] = a0;
    dst[(size_t)(row0 + r0 + 1) * DQ + fb] = a1;
}

// ---------------------------------------------------------------------------
// Kernel 2: one block per (b, g, 8-query tile); 512 threads = 8 waves,
// 256 blocks = 1 per CU.  Wave w owns keys [w*64, w*64+64).
//
// Scoring GEMM runs TRANSPOSED on MFMA:  D[ch,j] = W2^T (A-op)  x  h1^T (B-op)
// with v_mfma_f32_16x16x32_bf16 hi/lo 3-MFMA split (fp32-grade accuracy).
// Operand-swap puts ch into the register dim of C (row = lg*4+reg) and j into
// the lane dim (col = lr), so the W3 reduction is 4 in-lane FMAs + 2 shfl_xor
// instead of a 16-step cross-lane reduce.  Both fragments use the same k-map
// (k = H*32 + (e>>2)*16 + lg*4 + (e&3)); any bijection error cancels in the
// k-sum.  HW-verified facts only: operand row/col = lane&15; C/D col=lane&15,
// row=(lane>>4)*4+reg.
// ---------------------------------------------------------------------------
__global__ __launch_bounds__(512, 2) void attn_kernel(
    const float* __restrict__ QW1, const float* __restrict__ KW1,
    const float* __restrict__ Vp,
    const float* __restrict__ W2, const float* __restrict__ b2,
    const float* __restrict__ W3, const float* __restrict__ b3,
    const float* __restrict__ pos_add, const float* __restrict__ pos_mul,
    float* __restrict__ out)
{
    const int t = threadIdx.x;
    const int lane = t & 63, w = t >> 6;
    const int lg = lane >> 4, lr = lane & 15;
    const int ib = blockIdx.x & 63;
    const int g  = (blockIdx.x >> 6) & 1;
    const int b  = blockIdx.x >> 7;
    const int i0 = ib * 8;

    __shared__ __align__(16) float Qs[8][DGQ];        // 2KB
    __shared__ __align__(16) float logits[8][SQ];     // 16KB, raw a (pre b3)
    __shared__ __align__(16) float pbuf[SQ][8];       // 16KB, exp'd probs
    __shared__ __align__(16) float avs[8][8][DGQ];    // 16KB, [wave][q][dim]
    __shared__ float redm[8][8], reds[8][8];

    // stage the 8 query rows (group slice)
    Qs[t >> 6][t & 63] = QW1[((size_t)(b * SQ + i0 + (t >> 6))) * DQ +
                             g * DGQ + (t & 63)];

    // per-lane W2 fragments (A-operand, m=ch=lr), hi/lo split
    bf16x8 bhf[2], blf[2];
    #pragma unroll
    for (int H = 0; H < 2; ++H) {
        #pragma unroll
        for (int e = 0; e < 8; ++e) {
            const int k = H * 32 + (e >> 2) * 16 + lg * 4 + (e & 3);
            const float wv = W2[k * 16 + lr];
            const __bf16 hi = (__bf16)wv;
            bhf[H][e] = hi;
            blf[H][e] = (__bf16)(wv - (float)hi);
        }
    }
    float b2c[4], w3c[4];
    #pragma unroll
    for (int r = 0; r < 4; ++r) {
        b2c[r] = b2[lg * 4 + r];
        w3c[r] = W3[lg * 4 + r];
    }
    const float b3s = b3[0];
    const f32x4 zero4 = {0.f, 0.f, 0.f, 0.f};

    __syncthreads();

    // ---- main: 2 passes x (8 queries x 2 col-tiles of 16 keys) ----
    #pragma unroll
    for (int pass = 0; pass < 2; ++pass) {
        const int jb0 = w * 64 + pass * 32;
        f32x4 kreg[2][4];
        #pragma unroll
        for (int u = 0; u < 2; ++u) {
            const float* kr =
                KW1 + ((size_t)(b * SQ + jb0 + u * 16 + lr)) * DQ + g * DGQ;
            #pragma unroll
            for (int c = 0; c < 4; ++c)
                kreg[u][c] = *reinterpret_cast<const f32x4*>(
                    kr + (c & 1) * 16 + (c >> 1) * 32 + lg * 4);
        }
        #pragma unroll
        for (int i = 0; i < 8; ++i) {
            f32x4 qf[4];
            #pragma unroll
            for (int c = 0; c < 4; ++c)
                qf[c] = *reinterpret_cast<const f32x4*>(
                    &Qs[i][(c & 1) * 16 + (c >> 1) * 32 + lg * 4]);
            #pragma unroll
            for (int u = 0; u < 2; ++u) {
                f32x4 acc = zero4;
                #pragma unroll
                for (int H = 0; H < 2; ++H) {
                    f32x4 dd0 = qf[H * 2]     - kreg[u][H * 2];
                    f32x4 dd1 = qf[H * 2 + 1] - kreg[u][H * 2 + 1];
                    dd0 = __builtin_elementwise_max(dd0, zero4);  // v_pk_max
                    dd1 = __builtin_elementwise_max(dd1, zero4);
                    bf16x8 ah, al;
                    #pragma unroll
                    for (int e = 0; e < 4; ++e) {
                        const __bf16 hb = (__bf16)dd0[e];
                        ah[e] = hb;
                        al[e] = (__bf16)(dd0[e] - (float)hb);
                    }
                    #pragma unroll
                    for (int e = 0; e < 4; ++e) {
                        const __bf16 hb = (__bf16)dd1[e];
                        ah[4 + e] = hb;
                        al[4 + e] = (__bf16)(dd1[e] - (float)hb);
                    }
                    acc = __builtin_amdgcn_mfma_f32_16x16x32_bf16(
                        bhf[H], ah, acc, 0, 0, 0);
                    acc = __builtin_amdgcn_mfma_f32_16x16x32_bf16(
                        blf[H], ah, acc, 0, 0, 0);
                    acc = __builtin_amdgcn_mfma_f32_16x16x32_bf16(
                        bhf[H], al, acc, 0, 0, 0);
                }
                // s = sum_ch relu(D[ch,j]+b2[ch]) * W3[ch]; ch = lg*4+r
                float s = 0.f;
                #pragma unroll
                for (int r = 0; r < 4; ++r)
                    s = fmaf(fmaxf(acc[r] + b2c[r], 0.f), w3c[r], s);
                s += __shfl_xor(s, 16);                // reduce over lg groups
                s += __shfl_xor(s, 32);
                if (lg == 0) logits[i][jb0 + u * 16 + lr] = s;
            }
        }
    }
    __syncthreads();

    // ---- softmax: wave w owns key block w for ALL 8 queries ----
    const int jj = w * 64 + lane;
    float lgv[8];
    #pragma unroll
    for (int q = 0; q < 8; ++q) {
        const float raw = logits[q][jj];
        const size_t po = ((size_t)(g * SQ + i0 + q)) * SQ + jj;
        lgv[q] = fmaf(fmaxf(raw + b3s, 0.f), pos_mul[po], pos_add[po]);
    }
    #pragma unroll
    for (int q = 0; q < 8; ++q) {
        float m = lgv[q];
        #pragma unroll
        for (int off = 1; off < 64; off <<= 1)
            m = fmaxf(m, __shfl_xor(m, off));
        if (lane == 0) redm[q][w] = m;
    }
    __syncthreads();
    float Mq[8];
    #pragma unroll
    for (int q = 0; q < 8; ++q) {
        float M = redm[q][0];
        #pragma unroll
        for (int ww = 1; ww < 8; ++ww) M = fmaxf(M, redm[q][ww]);
        Mq[q] = M;
    }
    float e8[8];
    #pragma unroll
    for (int q = 0; q < 8; ++q) e8[q] = __expf(lgv[q] - Mq[q]);
    *reinterpret_cast<f32x4*>(&pbuf[jj][0]) = f32x4{e8[0], e8[1], e8[2], e8[3]};
    *reinterpret_cast<f32x4*>(&pbuf[jj][4]) = f32x4{e8[4], e8[5], e8[6], e8[7]};
    #pragma unroll
    for (int q = 0; q < 8; ++q) {
        float s = e8[q];
        #pragma unroll
        for (int off = 1; off < 64; off <<= 1) s += __shfl_xor(s, off);
        if (lane == 0) reds[q][w] = s;
    }
    __syncthreads();

    // ---- A@V: wave w handles key block w; lane = output dim; 8 queries ----
    f32x4 a0 = zero4, a1 = zero4;
    const float* vb =
        Vp + (((size_t)(b * SQ + w * 64)) * NGQ + g) * DGQ + lane;
    #pragma unroll 8
    for (int n = 0; n < 64; ++n) {
        const float v = vb[(size_t)n * (NGQ * DGQ)];      // coalesced, L2
        const f32x4 p0 = *reinterpret_cast<const f32x4*>(&pbuf[w * 64 + n][0]);
        const f32x4 p1 = *reinterpret_cast<const f32x4*>(&pbuf[w * 64 + n][4]);
        a0 += v * p0;                                     // v_pk_fma x2
        a1 += v * p1;
    }
    #pragma unroll
    for (int c = 0; c < 4; ++c) {
        avs[w][c][lane]     = a0[c];
        avs[w][4 + c][lane] = a1[c];
    }
    __syncthreads();

    const int q = t >> 6, d = t & 63;
    float sum = 0.f, den = 0.f;
    #pragma unroll
    for (int ww = 0; ww < 8; ++ww) {
        sum += avs[ww][q][d];
        den += reds[q][ww];
    }
    out[((size_t)(b * SQ + i0 + q)) * DQ + d * NGQ + g] = sum / den;
}

extern "C" void kernel_launch(void* const* d_in, const int* in_sizes, int n_in,
                              void* d_out, int out_size, void* d_ws, size_t ws_size,
                              hipStream_t stream) {
    const float* x       = (const float*)d_in[0];
    const float* pos_add = (const float*)d_in[1];
    const float* pos_mul = (const float*)d_in[2];
    const float* Wq      = (const float*)d_in[3];
    const float* Wk      = (const float*)d_in[4];
    const float* Wv      = (const float*)d_in[5];
    const float* W1      = (const float*)d_in[6];
    const float* b1      = (const float*)d_in[7];
    const float* W2      = (const float*)d_in[8];
    const float* b2      = (const float*)d_in[9];
    const float* W3      = (const float*)d_in[10];
    const float* b3      = (const float*)d_in[11];
    float* out = (float*)d_out;

    float* ws  = (float*)d_ws;
    float* QW1 = ws;
    float* KW1 = ws + 131072;
    float* Vp  = ws + 262144;

    proj_kernel<<<BQ * SQ / 4, 512, 0, stream>>>(x, Wq, Wk, Wv, W1, b1,
                                                 QW1, KW1, Vp);
    attn_kernel<<<BQ * NGQ * SQ / 8, 512, 0, stream>>>(QW1, KW1, Vp, W2, b2,
                                                       W3, b3, pos_add, pos_mul,
                                                       out);
}

// Round 4
// 113.820 us; speedup vs baseline: 1.0130x; 1.0130x over previous
//
#include <hip/hip_runtime.h>

// Problem constants (B=2, S=512, D=128, DG=64, NG=2)
#define BQ 2
#define SQ 512
#define DQ 128
#define DGQ 64
#define NGQ 2

typedef float f32x4 __attribute__((ext_vector_type(4)));
typedef __bf16 bf16x8 __attribute__((ext_vector_type(8)));

// ws layout (floats):
//   QW1 : [B*S][128]          @ 0        (= (x@Wq)@blkdiag(W1) + b1, per group)
//   KW1 : [B*S][128]          @ 131072
//   Vp  : [B*S][NG][DG]       @ 262144   (group-major V for coalesced A@V)

// ---------------------------------------------------------------------------
// Kernel 1: fused projections, 4 rows per block (256 blocks x 512 thr).
// Phase A: Q,K,V for 4 rows via split-K over 4 quarters; each weight load
// feeds 4 FMAs (weight L2 traffic 1024->256 block-reads = 48 MB total).
// Phase B: QW1 = Q@blkdiag(W1)+b1, KW1 = K@blkdiag(W1)  (linearity trick:
// relu((Q_i-K_j)@W1 + b1) == relu(QW1_i - KW1_j)).
// ---------------------------------------------------------------------------
__global__ __launch_bounds__(512) void proj_kernel(
    const float* __restrict__ x,
    const float* __restrict__ Wq, const float* __restrict__ Wk,
    const float* __restrict__ Wv,
    const float* __restrict__ W1, const float* __restrict__ b1,
    float* __restrict__ QW1, float* __restrict__ KW1, float* __restrict__ Vp)
{
    const int t = threadIdx.x;
    const int row0 = blockIdx.x * 4;
    __shared__ float xs[4][DQ];
    __shared__ float part[3][4][4][DQ];     // [mat][quarter][row][feat] 24KB
    __shared__ float qs[4][DQ], ks[4][DQ];

    ((float*)xs)[t] = x[(size_t)row0 * DQ + t];
    __syncthreads();

    const int f = t & 127, h = t >> 7;      // feature, K-quarter
    const int d0 = h * 32;
    float aq[4] = {0.f, 0.f, 0.f, 0.f};
    float ak[4] = {0.f, 0.f, 0.f, 0.f};
    float av[4] = {0.f, 0.f, 0.f, 0.f};
    #pragma unroll 8
    for (int d = 0; d < 32; ++d) {
        const size_t o = (size_t)(d0 + d) * DQ + f;   // 256B/wave coalesced
        const float wq = Wq[o], wk = Wk[o], wv = Wv[o];
        #pragma unroll
        for (int r = 0; r < 4; ++r) {
            const float xv = xs[r][d0 + d];            // LDS broadcast
            aq[r] = fmaf(xv, wq, aq[r]);
            ak[r] = fmaf(xv, wk, ak[r]);
            av[r] = fmaf(xv, wv, av[r]);
        }
    }
    #pragma unroll
    for (int r = 0; r < 4; ++r) {
        part[0][h][r][f] = aq[r];
        part[1][h][r][f] = ak[r];
        part[2][h][r][f] = av[r];
    }
    __syncthreads();

    const int fc = t & 127, sel = t >> 7;
    if (sel == 0) {
        #pragma unroll
        for (int r = 0; r < 4; ++r)
            qs[r][fc] = part[0][0][r][fc] + part[0][1][r][fc] +
                        part[0][2][r][fc] + part[0][3][r][fc];
    } else if (sel == 1) {
        #pragma unroll
        for (int r = 0; r < 4; ++r)
            ks[r][fc] = part[1][0][r][fc] + part[1][1][r][fc] +
                        part[1][2][r][fc] + part[1][3][r][fc];
    } else if (sel == 2) {
        #pragma unroll
        for (int r = 0; r < 4; ++r) {
            const float v = part[2][0][r][fc] + part[2][1][r][fc] +
                            part[2][2][r][fc] + part[2][3][r][fc];
            // feature fc = dg*NG+g  ->  Vp[row][g][dg]
            Vp[((size_t)(row0 + r) * NGQ + (fc & 1)) * DGQ + (fc >> 1)] = v;
        }
    }
    __syncthreads();

    // Phase B: 512 tasks = {q,k} x 2 row-pairs x 128 features
    const int fb = t & 127, rp = (t >> 7) & 1, side = t >> 8;
    const int g = fb >> 6, c = fb & 63;
    const float* src = side ? &ks[0][0] : &qs[0][0];
    const int r0 = rp * 2;
    float a0 = side ? 0.f : b1[c];
    float a1 = a0;
    #pragma unroll 8
    for (int e = 0; e < 64; ++e) {
        const float w1v = W1[e * DGQ + c];             // 256B/wave coalesced
        a0 = fmaf(src[r0 * DQ + g * 64 + e], w1v, a0);
        a1 = fmaf(src[(r0 + 1) * DQ + g * 64 + e], w1v, a1);
    }
    float* dst = side ? KW1 : QW1;
    dst[(size_t)(row0 + r0) * DQ + fb] = a0;
    dst[(size_t)(row0 + r0 + 1) * DQ + fb] = a1;
}

// ---------------------------------------------------------------------------
// Kernel 2: one block per (b, g, 4-query tile); 512 blocks x 512 thr = 8
// waves; __launch_bounds__(512,4) caps VGPR at 128 -> 2 blocks/CU so barrier
// phases of one block overlap MFMA/VALU of the other (round-3 post-mortem:
// 1 block/CU was the regression cause).  Wave w owns keys [w*64, w*64+64).
//
// Scoring GEMM runs TRANSPOSED on MFMA:  D[ch,j] = W2^T (A-op) x h1^T (B-op)
// with v_mfma_f32_16x16x32_bf16 hi/lo 3-MFMA split (fp32-grade accuracy).
// ch sits in the register dim of C (row = lg*4+reg), j in the lane dim, so
// the W3 reduction is 4 in-lane FMAs + 2 shfl_xor.  Both fragments use the
// same k-map (k = H*32 + (e>>2)*16 + lg*4 + (e&3)); any bijection error
// cancels in the k-sum.  HW-verified facts only: operand row/col = lane&15;
// C/D col=lane&15, row=(lane>>4)*4+reg.
//
// XCD chunk-swizzle (bijective, 512%8==0): the 64 blocks sharing one (b,g)
// K-slice land on the same XCD's L2.
// ---------------------------------------------------------------------------
__global__ __launch_bounds__(512, 4) void attn_kernel(
    const float* __restrict__ QW1, const float* __restrict__ KW1,
    const float* __restrict__ Vp,
    const float* __restrict__ W2, const float* __restrict__ b2,
    const float* __restrict__ W3, const float* __restrict__ b3,
    const float* __restrict__ pos_add, const float* __restrict__ pos_mul,
    float* __restrict__ out)
{
    const int t = threadIdx.x;
    const int lane = t & 63, w = t >> 6;
    const int lg = lane >> 4, lr = lane & 15;
    const int vid = ((blockIdx.x & 7) << 6) | (blockIdx.x >> 3);  // XCD chunk
    const int ib = vid & 127;
    const int g  = (vid >> 7) & 1;
    const int b  = vid >> 8;
    const int i0 = ib * 4;

    __shared__ __align__(16) float Qs[4][DGQ];        // 1KB
    __shared__ __align__(16) float logits[4][SQ];     // 8KB, raw a (pre b3)
    __shared__ __align__(16) float pbuf[SQ][4];       // 8KB, exp'd probs
    __shared__ __align__(16) float avs[8][4][DGQ];    // 8KB, [wave][q][dim]
    __shared__ float redm[4][8], reds[4][8];

    // stage the 4 query rows (group slice)
    if (t < 256)
        Qs[t >> 6][t & 63] = QW1[((size_t)(b * SQ + i0 + (t >> 6))) * DQ +
                                 g * DGQ + (t & 63)];

    // per-lane W2 fragments (A-operand, m=ch=lr), hi/lo split
    bf16x8 bhf[2], blf[2];
    #pragma unroll
    for (int H = 0; H < 2; ++H) {
        #pragma unroll
        for (int e = 0; e < 8; ++e) {
            const int k = H * 32 + (e >> 2) * 16 + lg * 4 + (e & 3);
            const float wv = W2[k * 16 + lr];
            const __bf16 hi = (__bf16)wv;
            bhf[H][e] = hi;
            blf[H][e] = (__bf16)(wv - (float)hi);
        }
    }
    float b2c[4], w3c[4];
    #pragma unroll
    for (int r = 0; r < 4; ++r) {
        b2c[r] = b2[lg * 4 + r];
        w3c[r] = W3[lg * 4 + r];
    }
    const float b3s = b3[0];
    const f32x4 zero4 = {0.f, 0.f, 0.f, 0.f};

    __syncthreads();

    // ---- main: 2 passes x (4 queries x 2 col-tiles of 16 keys) ----
    #pragma unroll
    for (int pass = 0; pass < 2; ++pass) {
        const int jb0 = w * 64 + pass * 32;
        f32x4 kreg[2][4];
        #pragma unroll
        for (int u = 0; u < 2; ++u) {
            const float* kr =
                KW1 + ((size_t)(b * SQ + jb0 + u * 16 + lr)) * DQ + g * DGQ;
            #pragma unroll
            for (int c = 0; c < 4; ++c)
                kreg[u][c] = *reinterpret_cast<const f32x4*>(
                    kr + (c & 1) * 16 + (c >> 1) * 32 + lg * 4);
        }
        #pragma unroll
        for (int i = 0; i < 4; ++i) {
            f32x4 qf[4];
            #pragma unroll
            for (int c = 0; c < 4; ++c)
                qf[c] = *reinterpret_cast<const f32x4*>(
                    &Qs[i][(c & 1) * 16 + (c >> 1) * 32 + lg * 4]);
            #pragma unroll
            for (int u = 0; u < 2; ++u) {
                f32x4 acc = zero4;
                #pragma unroll
                for (int H = 0; H < 2; ++H) {
                    f32x4 dd0 = qf[H * 2]     - kreg[u][H * 2];
                    f32x4 dd1 = qf[H * 2 + 1] - kreg[u][H * 2 + 1];
                    dd0 = __builtin_elementwise_max(dd0, zero4);  // v_pk_max
                    dd1 = __builtin_elementwise_max(dd1, zero4);
                    bf16x8 ah, al;
                    #pragma unroll
                    for (int e = 0; e < 4; ++e) {
                        const __bf16 hb = (__bf16)dd0[e];
                        ah[e] = hb;
                        al[e] = (__bf16)(dd0[e] - (float)hb);
                    }
                    #pragma unroll
                    for (int e = 0; e < 4; ++e) {
                        const __bf16 hb = (__bf16)dd1[e];
                        ah[4 + e] = hb;
                        al[4 + e] = (__bf16)(dd1[e] - (float)hb);
                    }
                    acc = __builtin_amdgcn_mfma_f32_16x16x32_bf16(
                        bhf[H], ah, acc, 0, 0, 0);
                    acc = __builtin_amdgcn_mfma_f32_16x16x32_bf16(
                        blf[H], ah, acc, 0, 0, 0);
                    acc = __builtin_amdgcn_mfma_f32_16x16x32_bf16(
                        bhf[H], al, acc, 0, 0, 0);
                }
                // s = sum_ch relu(D[ch,j]+b2[ch]) * W3[ch]; ch = lg*4+r
                float s = 0.f;
                #pragma unroll
                for (int r = 0; r < 4; ++r)
                    s = fmaf(fmaxf(acc[r] + b2c[r], 0.f), w3c[r], s);
                s += __shfl_xor(s, 16);                // reduce over lg groups
                s += __shfl_xor(s, 32);
                if (lg == 0) logits[i][jb0 + u * 16 + lr] = s;
            }
        }
    }
    __syncthreads();

    // ---- softmax: wave w owns key block w for ALL 4 queries ----
    const int jj = w * 64 + lane;
    float lgv[4];
    #pragma unroll
    for (int q = 0; q < 4; ++q) {
        const float raw = logits[q][jj];
        const size_t po = ((size_t)(g * SQ + i0 + q)) * SQ + jj;
        lgv[q] = fmaf(fmaxf(raw + b3s, 0.f), pos_mul[po], pos_add[po]);
    }
    #pragma unroll
    for (int q = 0; q < 4; ++q) {
        float m = lgv[q];
        #pragma unroll
        for (int off = 1; off < 64; off <<= 1)
            m = fmaxf(m, __shfl_xor(m, off));
        if (lane == 0) redm[q][w] = m;
    }
    __syncthreads();
    float e4[4];
    #pragma unroll
    for (int q = 0; q < 4; ++q) {
        float M = redm[q][0];
        #pragma unroll
        for (int ww = 1; ww < 8; ++ww) M = fmaxf(M, redm[q][ww]);
        e4[q] = __expf(lgv[q] - M);
    }
    *reinterpret_cast<f32x4*>(&pbuf[jj][0]) = f32x4{e4[0], e4[1], e4[2], e4[3]};
    #pragma unroll
    for (int q = 0; q < 4; ++q) {
        float s = e4[q];
        #pragma unroll
        for (int off = 1; off < 64; off <<= 1) s += __shfl_xor(s, off);
        if (lane == 0) reds[q][w] = s;
    }
    __syncthreads();

    // ---- A@V: wave w handles key block w; lane = output dim; 4 queries ----
    f32x4 a0 = zero4;
    const float* vb =
        Vp + (((size_t)(b * SQ + w * 64)) * NGQ + g) * DGQ + lane;
    #pragma unroll 8
    for (int n = 0; n < 64; ++n) {
        const float v = vb[(size_t)n * (NGQ * DGQ)];      // coalesced, L2
        const f32x4 p0 = *reinterpret_cast<const f32x4*>(&pbuf[w * 64 + n][0]);
        a0 += v * p0;                                     // v_pk_fma x2
    }
    #pragma unroll
    for (int c = 0; c < 4; ++c) avs[w][c][lane] = a0[c];
    __syncthreads();

    if (t < 256) {
        const int q = t >> 6, d = t & 63;
        float sum = 0.f, den = 0.f;
        #pragma unroll
        for (int ww = 0; ww < 8; ++ww) {
            sum += avs[ww][q][d];
            den += reds[q][ww];
        }
        out[((size_t)(b * SQ + i0 + q)) * DQ + d * NGQ + g] = sum / den;
    }
}

extern "C" void kernel_launch(void* const* d_in, const int* in_sizes, int n_in,
                              void* d_out, int out_size, void* d_ws, size_t ws_size,
                              hipStream_t stream) {
    const float* x       = (const float*)d_in[0];
    const float* pos_add = (const float*)d_in[1];
    const float* pos_mul = (const float*)d_in[2];
    const float* Wq      = (const float*)d_in[3];
    const float* Wk      = (const float*)d_in[4];
    const float* Wv      = (const float*)d_in[5];
    const float* W1      = (const float*)d_in[6];
    const float* b1      = (const float*)d_in[7];
    const float* W2      = (const float*)d_in[8];
    const float* b2      = (const float*)d_in[9];
    const float* W3      = (const float*)d_in[10];
    const float* b3      = (const float*)d_in[11];
    float* out = (float*)d_out;

    float* ws  = (float*)d_ws;
    float* QW1 = ws;
    float* KW1 = ws + 131072;
    float* Vp  = ws + 262144;

    proj_kernel<<<BQ * SQ / 4, 512, 0, stream>>>(x, Wq, Wk, Wv, W1, b1,
                                                 QW1, KW1, Vp);
    attn_kernel<<<BQ * NGQ * SQ / 4, 512, 0, stream>>>(QW1, KW1, Vp, W2, b2,
                                                       W3, b3, pos_add, pos_mul,
                                                       out);
}

// Round 5
// 110.404 us; speedup vs baseline: 1.0443x; 1.0309x over previous
//
#include <hip/hip_runtime.h>

// Problem constants (B=2, S=512, D=128, DG=64, NG=2)
#define BQ 2
#define SQ 512
#define DQ 128
#define DGQ 64
#define NGQ 2

typedef float f32x4 __attribute__((ext_vector_type(4)));
typedef __bf16 bf16x8 __attribute__((ext_vector_type(8)));

// ws layout (floats):
//   QW1 : [B*S][128]          @ 0        (= (x@Wq)@blkdiag(W1) + b1, per group)
//   KW1 : [B*S][128]          @ 131072
//   Vp  : [B*S][NG][DG]       @ 262144   (group-major V for coalesced A@V)

// ---------------------------------------------------------------------------
// Kernel 1: fused projections, 4 rows per block (256 blocks x 512 thr).
// Phase A: Q,K,V for 4 rows via split-K over 4 quarters; each weight load
// feeds 4 FMAs (weight L2 traffic 1024->256 block-reads = 48 MB total).
// Phase B: QW1 = Q@blkdiag(W1)+b1, KW1 = K@blkdiag(W1)  (linearity trick:
// relu((Q_i-K_j)@W1 + b1) == relu(QW1_i - KW1_j)).
// ---------------------------------------------------------------------------
__global__ __launch_bounds__(512) void proj_kernel(
    const float* __restrict__ x,
    const float* __restrict__ Wq, const float* __restrict__ Wk,
    const float* __restrict__ Wv,
    const float* __restrict__ W1, const float* __restrict__ b1,
    float* __restrict__ QW1, float* __restrict__ KW1, float* __restrict__ Vp)
{
    const int t = threadIdx.x;
    const int row0 = blockIdx.x * 4;
    __shared__ float xs[4][DQ];
    __shared__ float part[3][4][4][DQ];     // [mat][quarter][row][feat] 24KB
    __shared__ float qs[4][DQ], ks[4][DQ];

    ((float*)xs)[t] = x[(size_t)row0 * DQ + t];
    __syncthreads();

    const int f = t & 127, h = t >> 7;      // feature, K-quarter
    const int d0 = h * 32;
    float aq[4] = {0.f, 0.f, 0.f, 0.f};
    float ak[4] = {0.f, 0.f, 0.f, 0.f};
    float av[4] = {0.f, 0.f, 0.f, 0.f};
    #pragma unroll 8
    for (int d = 0; d < 32; ++d) {
        const size_t o = (size_t)(d0 + d) * DQ + f;   // 256B/wave coalesced
        const float wq = Wq[o], wk = Wk[o], wv = Wv[o];
        #pragma unroll
        for (int r = 0; r < 4; ++r) {
            const float xv = xs[r][d0 + d];            // LDS broadcast
            aq[r] = fmaf(xv, wq, aq[r]);
            ak[r] = fmaf(xv, wk, ak[r]);
            av[r] = fmaf(xv, wv, av[r]);
        }
    }
    #pragma unroll
    for (int r = 0; r < 4; ++r) {
        part[0][h][r][f] = aq[r];
        part[1][h][r][f] = ak[r];
        part[2][h][r][f] = av[r];
    }
    __syncthreads();

    const int fc = t & 127, sel = t >> 7;
    if (sel == 0) {
        #pragma unroll
        for (int r = 0; r < 4; ++r)
            qs[r][fc] = part[0][0][r][fc] + part[0][1][r][fc] +
                        part[0][2][r][fc] + part[0][3][r][fc];
    } else if (sel == 1) {
        #pragma unroll
        for (int r = 0; r < 4; ++r)
            ks[r][fc] = part[1][0][r][fc] + part[1][1][r][fc] +
                        part[1][2][r][fc] + part[1][3][r][fc];
    } else if (sel == 2) {
        #pragma unroll
        for (int r = 0; r < 4; ++r) {
            const float v = part[2][0][r][fc] + part[2][1][r][fc] +
                            part[2][2][r][fc] + part[2][3][r][fc];
            // feature fc = dg*NG+g  ->  Vp[row][g][dg]
            Vp[((size_t)(row0 + r) * NGQ + (fc & 1)) * DGQ + (fc >> 1)] = v;
        }
    }
    __syncthreads();

    // Phase B: 512 tasks = {q,k} x 2 row-pairs x 128 features
    const int fb = t & 127, rp = (t >> 7) & 1, side = t >> 8;
    const int g = fb >> 6, c = fb & 63;
    const float* src = side ? &ks[0][0] : &qs[0][0];
    const int r0 = rp * 2;
    float a0 = side ? 0.f : b1[c];
    float a1 = a0;
    #pragma unroll 8
    for (int e = 0; e < 64; ++e) {
        const float w1v = W1[e * DGQ + c];             // 256B/wave coalesced
        a0 = fmaf(src[r0 * DQ + g * 64 + e], w1v, a0);
        a1 = fmaf(src[(r0 + 1) * DQ + g * 64 + e], w1v, a1);
    }
    float* dst = side ? KW1 : QW1;
    dst[(size_t)(row0 + r0) * DQ + fb] = a0;
    dst[(size_t)(row0 + r0 + 1) * DQ + fb] = a1;
}

// ---------------------------------------------------------------------------
// Kernel 2: one block per (b, g, 4-query tile); 512 blocks x 512 thr = 8
// waves; __launch_bounds__(512,4) caps VGPR at 128 -> 2 blocks/CU so barrier
// phases of one block overlap MFMA/VALU of the other.
// NO XCD swizzle: all operands are L2/L3-resident (KW1 512KB, pos 8MB);
// swizzle is documented-negative in the L3-fit regime (m160, round-4 pm).
// Pos-bias loads are issued at block START (T14 early-issue): their ~1.3us
// of HBM latency hides under the main loop; vmcnt is in-order so the kreg
// waits subsume them.
//
// Scoring GEMM runs TRANSPOSED on MFMA:  D[ch,j] = W2^T (A-op) x h1^T (B-op)
// with v_mfma_f32_16x16x32_bf16 hi/lo 3-MFMA split (fp32-grade accuracy).
// ch sits in the register dim of C (row = lg*4+reg), j in the lane dim, so
// the W3 reduction is 4 in-lane FMAs + 2 shfl_xor.  Both fragments use the
// same k-map (k = H*32 + (e>>2)*16 + lg*4 + (e&3)); any bijection error
// cancels in the k-sum.  HW-verified facts only: operand row/col = lane&15;
// C/D col=lane&15, row=(lane>>4)*4+reg.
// ---------------------------------------------------------------------------
__global__ __launch_bounds__(512, 4) void attn_kernel(
    const float* __restrict__ QW1, const float* __restrict__ KW1,
    const float* __restrict__ Vp,
    const float* __restrict__ W2, const float* __restrict__ b2,
    const float* __restrict__ W3, const float* __restrict__ b3,
    const float* __restrict__ pos_add, const float* __restrict__ pos_mul,
    float* __restrict__ out)
{
    const int t = threadIdx.x;
    const int lane = t & 63, w = t >> 6;
    const int lg = lane >> 4, lr = lane & 15;
    const int ib = blockIdx.x & 127;
    const int g  = (blockIdx.x >> 7) & 1;
    const int b  = blockIdx.x >> 8;
    const int i0 = ib * 4;

    __shared__ __align__(16) float Qs[4][DGQ];        // 1KB
    __shared__ __align__(16) float logits[4][SQ];     // 8KB, raw a (pre b3)
    __shared__ __align__(16) float pbuf[SQ][4];       // 8KB, exp'd probs
    __shared__ __align__(16) float avs[8][4][DGQ];    // 8KB, [wave][q][dim]
    __shared__ float redm[4][8], reds[4][8];

    // ---- early-issue: pos bias for this lane's key column (HBM, ~1.3us
    // total across the grid) -- consumed only after the main loop.
    const int jj = w * 64 + lane;
    float pmv[4], pav[4];
    #pragma unroll
    for (int q = 0; q < 4; ++q) {
        const size_t po = ((size_t)(g * SQ + i0 + q)) * SQ + jj;
        pmv[q] = pos_mul[po];
        pav[q] = pos_add[po];
    }

    // stage the 4 query rows (group slice)
    if (t < 256)
        Qs[t >> 6][t & 63] = QW1[((size_t)(b * SQ + i0 + (t >> 6))) * DQ +
                                 g * DGQ + (t & 63)];

    // per-lane W2 fragments (A-operand, m=ch=lr), hi/lo split
    bf16x8 bhf[2], blf[2];
    #pragma unroll
    for (int H = 0; H < 2; ++H) {
        #pragma unroll
        for (int e = 0; e < 8; ++e) {
            const int k = H * 32 + (e >> 2) * 16 + lg * 4 + (e & 3);
            const float wv = W2[k * 16 + lr];
            const __bf16 hi = (__bf16)wv;
            bhf[H][e] = hi;
            blf[H][e] = (__bf16)(wv - (float)hi);
        }
    }
    float b2c[4], w3c[4];
    #pragma unroll
    for (int r = 0; r < 4; ++r) {
        b2c[r] = b2[lg * 4 + r];
        w3c[r] = W3[lg * 4 + r];
    }
    const float b3s = b3[0];
    const f32x4 zero4 = {0.f, 0.f, 0.f, 0.f};

    __syncthreads();

    // ---- main: 2 passes x (4 queries x 2 col-tiles of 16 keys) ----
    #pragma unroll
    for (int pass = 0; pass < 2; ++pass) {
        const int jb0 = w * 64 + pass * 32;
        f32x4 kreg[2][4];
        #pragma unroll
        for (int u = 0; u < 2; ++u) {
            const float* kr =
                KW1 + ((size_t)(b * SQ + jb0 + u * 16 + lr)) * DQ + g * DGQ;
            #pragma unroll
            for (int c = 0; c < 4; ++c)
                kreg[u][c] = *reinterpret_cast<const f32x4*>(
                    kr + (c & 1) * 16 + (c >> 1) * 32 + lg * 4);
        }
        #pragma unroll
        for (int i = 0; i < 4; ++i) {
            f32x4 qf[4];
            #pragma unroll
            for (int c = 0; c < 4; ++c)
                qf[c] = *reinterpret_cast<const f32x4*>(
                    &Qs[i][(c & 1) * 16 + (c >> 1) * 32 + lg * 4]);
            #pragma unroll
            for (int u = 0; u < 2; ++u) {
                f32x4 acc = zero4;
                #pragma unroll
                for (int H = 0; H < 2; ++H) {
                    f32x4 dd0 = qf[H * 2]     - kreg[u][H * 2];
                    f32x4 dd1 = qf[H * 2 + 1] - kreg[u][H * 2 + 1];
                    dd0 = __builtin_elementwise_max(dd0, zero4);  // v_pk_max
                    dd1 = __builtin_elementwise_max(dd1, zero4);
                    bf16x8 ah, al;
                    #pragma unroll
                    for (int e = 0; e < 4; ++e) {
                        const __bf16 hb = (__bf16)dd0[e];
                        ah[e] = hb;
                        al[e] = (__bf16)(dd0[e] - (float)hb);
                    }
                    #pragma unroll
                    for (int e = 0; e < 4; ++e) {
                        const __bf16 hb = (__bf16)dd1[e];
                        ah[4 + e] = hb;
                        al[4 + e] = (__bf16)(dd1[e] - (float)hb);
                    }
                    acc = __builtin_amdgcn_mfma_f32_16x16x32_bf16(
                        bhf[H], ah, acc, 0, 0, 0);
                    acc = __builtin_amdgcn_mfma_f32_16x16x32_bf16(
                        blf[H], ah, acc, 0, 0, 0);
                    acc = __builtin_amdgcn_mfma_f32_16x16x32_bf16(
                        bhf[H], al, acc, 0, 0, 0);
                }
                // s = sum_ch relu(D[ch,j]+b2[ch]) * W3[ch]; ch = lg*4+r
                float s = 0.f;
                #pragma unroll
                for (int r = 0; r < 4; ++r)
                    s = fmaf(fmaxf(acc[r] + b2c[r], 0.f), w3c[r], s);
                s += __shfl_xor(s, 16);                // reduce over lg groups
                s += __shfl_xor(s, 32);
                if (lg == 0) logits[i][jb0 + u * 16 + lr] = s;
            }
        }
    }
    __syncthreads();

    // ---- softmax: wave w owns key block w for ALL 4 queries ----
    float lgv[4];
    #pragma unroll
    for (int q = 0; q < 4; ++q) {
        const float raw = logits[q][jj];
        lgv[q] = fmaf(fmaxf(raw + b3s, 0.f), pmv[q], pav[q]);
    }
    #pragma unroll
    for (int q = 0; q < 4; ++q) {
        float m = lgv[q];
        #pragma unroll
        for (int off = 1; off < 64; off <<= 1)
            m = fmaxf(m, __shfl_xor(m, off));
        if (lane == 0) redm[q][w] = m;
    }
    __syncthreads();
    float e4[4];
    #pragma unroll
    for (int q = 0; q < 4; ++q) {
        float M = redm[q][0];
        #pragma unroll
        for (int ww = 1; ww < 8; ++ww) M = fmaxf(M, redm[q][ww]);
        e4[q] = __expf(lgv[q] - M);
    }
    *reinterpret_cast<f32x4*>(&pbuf[jj][0]) = f32x4{e4[0], e4[1], e4[2], e4[3]};
    #pragma unroll
    for (int q = 0; q < 4; ++q) {
        float s = e4[q];
        #pragma unroll
        for (int off = 1; off < 64; off <<= 1) s += __shfl_xor(s, off);
        if (lane == 0) reds[q][w] = s;
    }
    __syncthreads();

    // ---- A@V: wave w handles key block w; lane = output dim; 4 queries ----
    f32x4 a0 = zero4;
    const float* vb =
        Vp + (((size_t)(b * SQ + w * 64)) * NGQ + g) * DGQ + lane;
    #pragma unroll 8
    for (int n = 0; n < 64; ++n) {
        const float v = vb[(size_t)n * (NGQ * DGQ)];      // coalesced, L2
        const f32x4 p0 = *reinterpret_cast<const f32x4*>(&pbuf[w * 64 + n][0]);
        a0 += v * p0;                                     // v_pk_fma x2
    }
    #pragma unroll
    for (int c = 0; c < 4; ++c) avs[w][c][lane] = a0[c];
    __syncthreads();

    if (t < 256) {
        const int q = t >> 6, d = t & 63;
        float sum = 0.f, den = 0.f;
        #pragma unroll
        for (int ww = 0; ww < 8; ++ww) {
            sum += avs[ww][q][d];
            den += reds[q][ww];
        }
        out[((size_t)(b * SQ + i0 + q)) * DQ + d * NGQ + g] = sum / den;
    }
}

extern "C" void kernel_launch(void* const* d_in, const int* in_sizes, int n_in,
                              void* d_out, int out_size, void* d_ws, size_t ws_size,
                              hipStream_t stream) {
    const float* x       = (const float*)d_in[0];
    const float* pos_add = (const float*)d_in[1];
    const float* pos_mul = (const float*)d_in[2];
    const float* Wq      = (const float*)d_in[3];
    const float* Wk      = (const float*)d_in[4];
    const float* Wv      = (const float*)d_in[5];
    const float* W1      = (const float*)d_in[6];
    const float* b1      = (const float*)d_in[7];
    const float* W2      = (const float*)d_in[8];
    const float* b2      = (const float*)d_in[9];
    const float* W3      = (const float*)d_in[10];
    const float* b3      = (const float*)d_in[11];
    float* out = (float*)d_out;

    float* ws  = (float*)d_ws;
    float* QW1 = ws;
    float* KW1 = ws + 131072;
    float* Vp  = ws + 262144;

    proj_kernel<<<BQ * SQ / 4, 512, 0, stream>>>(x, Wq, Wk, Wv, W1, b1,
                                                 QW1, KW1, Vp);
    attn_kernel<<<BQ * NGQ * SQ / 4, 512, 0, stream>>>(QW1, KW1, Vp, W2, b2,
                                                       W3, b3, pos_add, pos_mul,
                                                       out);
}